// Round 2
// baseline (6576.459 us; speedup 1.0000x reference)
//
#include <hip/hip_runtime.h>
#include <cmath>

#define BATCH 128
#define TLEN  256
#define HDIM  1024
#define CDIM  10
#define NT    1024
#define NWG   256

typedef unsigned long long u64;
typedef unsigned int u32;

// h state, double buffered, k-major, u64 = 2 packed floats: g_hx[buf][j][b/2].
// ALL h accesses are relaxed agent-scope atomics (sc1) -> no cache fences;
// x/W/bias stay warm in L1/L2 across all 256 steps.
__device__ u64 g_hx[2][HDIM][BATCH / 2];

__device__ __forceinline__ float4 ld4(const float* p) { return *(const float4*)p; }

__device__ __forceinline__ u64 aload(const u64* p) {
    return __hip_atomic_load(p, __ATOMIC_RELAXED, __HIP_MEMORY_SCOPE_AGENT);
}
__device__ __forceinline__ void astore(u64* p, u64 v) {
    __hip_atomic_store(p, v, __ATOMIC_RELAXED, __HIP_MEMORY_SCOPE_AGENT);
}
__device__ __forceinline__ void astore32(u32* p, u32 v) {
    __hip_atomic_store(p, v, __ATOMIC_RELAXED, __HIP_MEMORY_SCOPE_AGENT);
}

// R13: LDS-only barrier. hipcc's __syncthreads() drains vmcnt(0) (full MALL
// latency, ~900 cyc) before s_barrier -- that killed the A/B global prefetch
// twice per cc-iteration. Intra-block barriers in the hot loop only protect
// LDS double-buffer handoffs, so lgkmcnt(0) is the only wait required; the
// in-flight global loads are register-private and get compiler-inserted
// COUNTED vmcnt waits at their ds_write use points one iteration later
// (T4: never drain vmcnt to 0 in the main loop).
// Uniform execution: cc-loop is unroll-1 with uniform trip count, no
// barrier sits under a divergent branch -> s_barrier cannot deadlock.
__device__ __forceinline__ void barrier_lds() {
    asm volatile("s_waitcnt lgkmcnt(0)\n\ts_barrier" ::: "memory");
}

// Group barrier (R11/R12-proven): parallel arrivals on 128 distinct flags,
// per-wave self-release poll, monotonic targets, bounded spin.
// GROUP-CONFINEMENT INVARIANT (R10 lesson): everything a block touches
// between barriers is produced by its OWN b-half group.
// Keeps its explicit vmcnt(0): it is the h-publish release fence.
__device__ __forceinline__ void gbar2(u32* flags, int grp, int idx, u32 target) {
    asm volatile("s_waitcnt vmcnt(0)" ::: "memory");
    __syncthreads();
    if (threadIdx.x == 0)
        astore32(flags + grp * 128 + idx, target);
    const u64* base = (const u64*)(flags + grp * 128) + (threadIdx.x & 63);
    int guard = 0;
    for (;;) {
        const u64 v = aload(base);
        const bool ok = ((u32)v >= target) && ((u32)(v >> 32) >= target);
        if (__all(ok) || ++guard > (1 << 20)) break;
        __builtin_amdgcn_s_sleep(1);
    }
}

#define FMA4(d, s, v) do { (d).x = fmaf((s), (v).x, (d).x); (d).y = fmaf((s), (v).y, (d).y); \
                           (d).z = fmaf((s), (v).z, (d).z); (d).w = fmaf((s), (v).w, (d).w); } while (0)
#define ADD4(d, s)     do { (d).x += (s).x; (d).y += (s).y; (d).z += (s).z; (d).w += (s).w; } while (0)

// Block: 8 j x 64 b. 16 waves: wave = jq*4 + kh (jq: j-pair, kh: k-quarter).
// Per chunk each lane handles exactly one k (kc = kh*8 + ks) -> no kk loop.
// 4 waves/SIMD (R12 lesson: at 2 waves/SIMD pipes add instead of overlap).
// Reduction: recursive-halving shfl butterfly (56 shfl vs 192) + 2-stage
// cross-kh exchange through LDS aliased onto the dead sH buffers; epilogue
// split across kh0 (cell0) / kh2 (cell1). All register indices static.
__global__ void __launch_bounds__(NT, 1)
lstm_fused(const float* __restrict__ x,
           const float* __restrict__ Wgx, const float* __restrict__ Wgh, const float* __restrict__ bg,
           const float* __restrict__ Wix, const float* __restrict__ Wih, const float* __restrict__ bi,
           const float* __restrict__ Wfx, const float* __restrict__ Wfh, const float* __restrict__ bf,
           const float* __restrict__ Wox, const float* __restrict__ Woh, const float* __restrict__ bo,
           const float* __restrict__ Wph, const float* __restrict__ bp,
           u32* __restrict__ flags, float* __restrict__ out)
{
    __shared__ float sW[8][HDIM][4];            // [j_local][k][gate], 128 KB
    __shared__ __align__(16) float sHraw[2 * 32 * 68];   // h dbuf, 17 KB; aliased by sS after last chunk
#define SH(B, K) (&sHraw[(B) * 2176 + (K) * 68])

    const int tid  = threadIdx.x;
    const int wave = tid >> 6;          // 0..15
    const int jq   = wave >> 2;         // j-pair index (0..3)
    const int kh   = wave & 3;          // k-quarter within chunk
    const int lane = tid & 63;
    const int ks   = lane & 7;
    const int bo8  = lane >> 3;
    const int rgB  = blockIdx.x >> 1;   // j in [8*rgB, 8*rgB+8)  == index in group
    const int bgB  = blockIdx.x & 1;    // b in [64*bgB, 64*bgB+64) == group id

    // ---- stage W once, gate-interleaved (1024 threads: 4 rows per pass) ----
    {
        auto stageW = [&](const float* Wsrc, int g) {
            #pragma unroll
            for (int it = 0; it < 2; ++it) {
                const int row = it * 4 + (tid >> 8);     // 0..7
                const int c4  = tid & 255;               // float4 column
                const float4 v = ld4(Wsrc + (size_t)(rgB * 8 + row) * HDIM + c4 * 4);
                sW[row][c4 * 4 + 0][g] = v.x;
                sW[row][c4 * 4 + 1][g] = v.y;
                sW[row][c4 * 4 + 2][g] = v.z;
                sW[row][c4 * 4 + 3][g] = v.w;
            }
        };
        stageW(Wgh, 0); stageW(Wih, 1); stageW(Wfh, 2); stageW(Woh, 3);
    }

    // epilogue cells: j = rgB*8 + jq*2 + (ks>>2); b = bgB*64 + bo8*8 + (ks&3)*2 + cell.
    // kh0 wave owns cell 0, kh2 wave owns cell 1 (split epilogue).
    const int jc = rgB * 8 + jq * 2 + (ks >> 2);
    const float4 wx4 = make_float4(Wgx[jc], Wix[jc], Wfx[jc], Wox[jc]);
    const float4 b4  = make_float4(bg[jc], bi[jc], bf[jc], bo[jc]);
    const int bloc = bgB * 64 + bo8 * 8 + (ks & 3) * 2;   // cell-0 batch index
    float cst = 0.f;                                       // my cell's c-state

    // zero h0 -- OWN b-half only: 8 j-rows x 32 u64
    if (tid < 256)
        astore(&g_hx[0][rgB * 8 + (tid >> 5)][bgB * 32 + (tid & 31)], 0ull);

    gbar2(flags, bgB, rgB, 1u);

    const int skc = tid >> 5;                   // staging: k within chunk (0..31)
    const int sbu = tid & 31;                   // staging: u64 col within 32
    const int hb0 = bgB * 32 + sbu;             // staging: u64 offset in g_hx row
    // u64 index of this thread's staging slot inside a buffer
    const int swA = (0 * 2176 + 0) / 2;         // buf0 base (u64 units)
    const int swB = (1 * 2176 + 0) / 2;         // buf1 base
    const int swoff = (skc * 68) / 2 + sbu;

#define COMP(C, BUF)                                                            \
    {                                                                           \
        const int kc_ = kh * 8 + ks;                                            \
        const float4 w0 = ld4(&sW[jq * 2 + 0][(C) * 32 + kc_][0]);              \
        const float4 w1 = ld4(&sW[jq * 2 + 1][(C) * 32 + kc_][0]);              \
        const float* hr = SH(BUF, kc_);                                         \
        const float4 hA = ld4(hr + bo8 * 8);                                    \
        const float4 hB = ld4(hr + bo8 * 8 + 4);                                \
        FMA4(acc[0][0], hA.x, w0); FMA4(acc[0][1], hA.y, w0);                   \
        FMA4(acc[0][2], hA.z, w0); FMA4(acc[0][3], hA.w, w0);                   \
        FMA4(acc[0][4], hB.x, w0); FMA4(acc[0][5], hB.y, w0);                   \
        FMA4(acc[0][6], hB.z, w0); FMA4(acc[0][7], hB.w, w0);                   \
        FMA4(acc[1][0], hA.x, w1); FMA4(acc[1][1], hA.y, w1);                   \
        FMA4(acc[1][2], hA.z, w1); FMA4(acc[1][3], hA.w, w1);                   \
        FMA4(acc[1][4], hB.x, w1); FMA4(acc[1][5], hB.y, w1);                   \
        FMA4(acc[1][6], hB.z, w1); FMA4(acc[1][7], hB.w, w1);                   \
    }

    for (int t = 0; t < TLEN; ++t) {
        const u64* hc = &g_hx[t & 1][0][0];
        u32*       hn32 = (u32*)&g_hx[(t + 1) & 1][0][0];

        // x for my epilogue cell (kh0 -> b, kh2 -> b+1), L1-warm
        float xv = 0.f;
        if ((kh & 1) == 0)
            xv = x[(size_t)(bloc + (kh >> 1)) * TLEN + t];

        const u64* hrow = hc + (size_t)skc * 64 + hb0;
        {   // stage chunk 0 directly (exposed ~0.4 us once/step)
            ((u64*)sHraw)[swA + swoff] = aload(hrow);
        }
        u64 A = aload(hrow + 2048);     // chunk 1
        u64 B = aload(hrow + 4096);     // chunk 2
        barrier_lds();                  // chunk-0 ds_write done; A/B stay in flight

        float4 acc[2][8];   // [j_local][b]; components = 4 gates. STATIC indices only.
        #pragma unroll
        for (int jl = 0; jl < 2; ++jl)
            #pragma unroll
            for (int cb = 0; cb < 8; ++cb)
                acc[jl][cb] = make_float4(0.f, 0.f, 0.f, 0.f);

        #pragma unroll 1
        for (int cc = 0; cc < 16; ++cc) {
            const int e0 = cc * 2;
            COMP(e0, 0);
            ((u64*)sHraw)[swB + swoff] = A;                  // chunk e0+1
            if (e0 + 3 < 32) A = aload(hrow + (size_t)(e0 + 3) * 2048);
            barrier_lds();
            COMP(e0 + 1, 1);
            if (e0 + 2 < 32) ((u64*)sHraw)[swA + swoff] = B; // chunk e0+2
            if (e0 + 4 < 32) B = aload(hrow + (size_t)(e0 + 4) * 2048);
            barrier_lds();
        }
        // loop-final barrier: all sH reads done -> sS alias safe

        // ---- intra-wave recursive-halving reduction over ks (56 shfl) ----
        float4 r1[8];
        #pragma unroll
        for (int i = 0; i < 8; ++i) {
            const float4 fs = (ks & 4) ? acc[0][i] : acc[1][i];
            float4 fr;
            fr.x = __shfl_xor(fs.x, 4); fr.y = __shfl_xor(fs.y, 4);
            fr.z = __shfl_xor(fs.z, 4); fr.w = __shfl_xor(fs.w, 4);
            const float4 fk = (ks & 4) ? acc[1][i] : acc[0][i];
            r1[i] = make_float4(fk.x + fr.x, fk.y + fr.y, fk.z + fr.z, fk.w + fr.w);
        }
        float4 r2[4];
        #pragma unroll
        for (int i = 0; i < 4; ++i) {
            const float4 fs = (ks & 2) ? r1[i] : r1[i + 4];
            float4 fr;
            fr.x = __shfl_xor(fs.x, 2); fr.y = __shfl_xor(fs.y, 2);
            fr.z = __shfl_xor(fs.z, 2); fr.w = __shfl_xor(fs.w, 2);
            const float4 fk = (ks & 2) ? r1[i + 4] : r1[i];
            r2[i] = make_float4(fk.x + fr.x, fk.y + fr.y, fk.z + fr.z, fk.w + fr.w);
        }
        float4 q0, q1;
        {
            const float4 fs0 = (ks & 1) ? r2[0] : r2[2];
            const float4 fs1 = (ks & 1) ? r2[1] : r2[3];
            float4 fr0, fr1;
            fr0.x = __shfl_xor(fs0.x, 1); fr0.y = __shfl_xor(fs0.y, 1);
            fr0.z = __shfl_xor(fs0.z, 1); fr0.w = __shfl_xor(fs0.w, 1);
            fr1.x = __shfl_xor(fs1.x, 1); fr1.y = __shfl_xor(fs1.y, 1);
            fr1.z = __shfl_xor(fs1.z, 1); fr1.w = __shfl_xor(fs1.w, 1);
            const float4 fk0 = (ks & 1) ? r2[2] : r2[0];
            const float4 fk1 = (ks & 1) ? r2[3] : r2[1];
            q0 = make_float4(fk0.x + fr0.x, fk0.y + fr0.y, fk0.z + fr0.z, fk0.w + fr0.w);
            q1 = make_float4(fk1.x + fr1.x, fk1.y + fr1.y, fk1.z + fr1.z, fk1.w + fr1.w);
        }
        // q0,q1 = partial (this kh) preacts for cells (jc, bloc) and (jc, bloc+1)

        // ---- cross-kh reduction via LDS aliased onto dead sH ----
        float4* sS = (float4*)sHraw;    // 1024 f4 = 16 KB <= 17.4 KB
        if (kh & 1) {                   // kh1 -> slot(jq,0), kh3 -> slot(jq,1)
            const int sl = ((jq * 2 + (kh >> 1)) * 64 + lane) * 2;
            sS[sl]     = q0;
            sS[sl + 1] = q1;
        }
        barrier_lds();
        if ((kh & 1) == 0) {            // kh0 adds kh1; kh2 adds kh3
            const int sl = ((jq * 2 + (kh >> 1)) * 64 + lane) * 2;
            ADD4(q0, sS[sl]);
            ADD4(q1, sS[sl + 1]);
        }
        // stage 2: kh0 surrenders q1, kh2 surrenders q0 (each keeps its cell)
        if (kh == 0) sS[((jq * 2 + 0) * 64 + lane) * 2 + 1] = q1;
        if (kh == 2) sS[((jq * 2 + 1) * 64 + lane) * 2 + 0] = q0;
        barrier_lds();

        if ((kh & 1) == 0) {
            float4 qq;
            if (kh == 0) {
                ADD4(q0, sS[((jq * 2 + 1) * 64 + lane) * 2 + 0]);
                qq = q0;
            } else {
                ADD4(q1, sS[((jq * 2 + 0) * 64 + lane) * 2 + 1]);
                qq = q1;
            }
            FMA4(qq, xv, wx4);
            qq.x += b4.x; qq.y += b4.y; qq.z += b4.z; qq.w += b4.w;
            const float g_ = tanhf(qq.x);
            const float i_ = 1.f / (1.f + expf(-qq.y));
            const float f_ = 1.f / (1.f + expf(-qq.z));
            const float o_ = 1.f / (1.f + expf(-qq.w));
            cst = g_ * i_ + cst * f_;
            const float hv = tanhf(cst) * o_;
            u32 bits; __builtin_memcpy(&bits, &hv, 4);
            astore32(hn32 + (size_t)jc * 128 + bloc + (kh >> 1), bits);
        }

        gbar2(flags, bgB, rgB, (u32)(t + 2));
    } // t
#undef COMP

    // ---- final projection: out = h_final @ W_ph + bias_p (final h in buf 0).
    // Group-confinement: block projects b = bgB*64 + rgB (own b-half).
    // h read sc1 (no inv anywhere -> cached h copies may be stale).
    if (rgB < 64) {
        const int b = bgB * 64 + rgB;
        float part[CDIM];
        #pragma unroll
        for (int c2 = 0; c2 < CDIM; ++c2) part[c2] = 0.f;
        for (int k = tid; k < HDIM; k += NT) {
            const u64 hvu = aload(&g_hx[0][k][b >> 1]);
            float2 hv2; __builtin_memcpy(&hv2, &hvu, 8);
            const float hvv = (b & 1) ? hv2.y : hv2.x;
            #pragma unroll
            for (int c2 = 0; c2 < CDIM; ++c2)
                part[c2] = fmaf(hvv, Wph[(size_t)k * CDIM + c2], part[c2]);
        }
        float* red = (float*)&sW[0][0][0];   // reuse dead W LDS (48 KB needed)
        #pragma unroll
        for (int c2 = 0; c2 < CDIM; ++c2) red[tid * 12 + c2] = part[c2];
        __syncthreads();
        for (int s = NT / 2; s > 0; s >>= 1) {
            if (tid < s) {
                #pragma unroll
                for (int c2 = 0; c2 < CDIM; ++c2)
                    red[tid * 12 + c2] += red[(tid + s) * 12 + c2];
            }
            __syncthreads();
        }
        if (tid < CDIM) out[(size_t)b * CDIM + tid] = red[tid] + bp[tid];
    }
}

extern "C" void kernel_launch(void* const* d_in, const int* in_sizes, int n_in,
                              void* d_out, int out_size, void* d_ws, size_t ws_size,
                              hipStream_t stream) {
    const float* x   = (const float*)d_in[0];
    const float* Wgx = (const float*)d_in[1];
    const float* Wgh = (const float*)d_in[2];
    const float* bg  = (const float*)d_in[3];
    const float* Wix = (const float*)d_in[4];
    const float* Wih = (const float*)d_in[5];
    const float* bi  = (const float*)d_in[6];
    const float* Wfx = (const float*)d_in[7];
    const float* Wfh = (const float*)d_in[8];
    const float* bf  = (const float*)d_in[9];
    const float* Wox = (const float*)d_in[10];
    const float* Woh = (const float*)d_in[11];
    const float* bo  = (const float*)d_in[12];
    const float* Wph = (const float*)d_in[13];
    const float* bp  = (const float*)d_in[14];
    u32* flags = (u32*)d_ws;               // u32[2][128] monotonic arrival flags
    float* out = (float*)d_out;

    hipMemsetAsync(d_ws, 0, 2 * 128 * sizeof(u32), stream);   // capturable node

    void* args[] = {&x, &Wgx, &Wgh, &bg, &Wix, &Wih, &bi, &Wfx, &Wfh, &bf,
                    &Wox, &Woh, &bo, &Wph, &bp, &flags, &out};
    hipError_t rc = hipLaunchCooperativeKernel((void*)lstm_fused, dim3(NWG), dim3(NT),
                                               args, 0, stream);
    if (rc != hipSuccess) {
        // Custom barrier needs no cooperative-runtime support; 256 blocks at
        // 1 block/CU are fully co-resident under a regular launch too.
        lstm_fused<<<dim3(NWG), dim3(NT), 0, stream>>>(
            x, Wgx, Wgh, bg, Wix, Wih, bi, Wfx, Wfh, bf,
            Wox, Woh, bo, Wph, bp, flags, out);
    }
}

// Round 3
// 6366.960 us; speedup vs baseline: 1.0329x; 1.0329x over previous
//
#include <hip/hip_runtime.h>
#include <cmath>

#define BATCH 128
#define TLEN  256
#define HDIM  1024
#define CDIM  10
#define NT    1024
#define NWG   256

typedef unsigned long long u64;
typedef unsigned int u32;

// h state, TRIPLE buffered (R14), k-major, u64 = 2 packed floats: g_hx[buf][j][b/2].
// Iteration t consumes buf[t%3], produces buf[(t+1)%3]. 3 buffers are sufficient:
// a block can only write production t+2 after its chunk-gates saw ALL 128 flags
// >= t+2, i.e. every group block finished iteration t (and thus all its reads of
// production t, which lives in the same buffer slot (t+2)%3 == (t-1)%3). QED.
// ALL h accesses are relaxed agent-scope atomics -> served at MALL, no fences.
__device__ u64 g_hx[3][HDIM][BATCH / 2];

__device__ __forceinline__ float4 ld4(const float* p) { return *(const float4*)p; }

__device__ __forceinline__ u64 aload(const u64* p) {
    return __hip_atomic_load(p, __ATOMIC_RELAXED, __HIP_MEMORY_SCOPE_AGENT);
}
__device__ __forceinline__ void astore(u64* p, u64 v) {
    __hip_atomic_store(p, v, __ATOMIC_RELAXED, __HIP_MEMORY_SCOPE_AGENT);
}
__device__ __forceinline__ void astore32(u32* p, u32 v) {
    __hip_atomic_store(p, v, __ATOMIC_RELAXED, __HIP_MEMORY_SCOPE_AGENT);
}

// R13 (kept): LDS-only barrier -- intra-block barriers only protect LDS
// double-buffer handoffs; counted vmcnt stays in flight across them.
__device__ __forceinline__ void barrier_lds() {
    asm volatile("s_waitcnt lgkmcnt(0)\n\ts_barrier" ::: "memory");
}

// R14 dataflow sync. flags[grp*128 + z] = number of h-productions completed by
// block z of group grp (monotonic; memset to 0 per launch; init production = 1).
// Chunk c's producers are blocks 4c..4c+3 (chunk = 32 k-rows, 8 j-rows/block).

// Spin until flags[0..15] >= target (covers chunks 0..3, the step-top stages).
__device__ __forceinline__ void gate16(const u32* flags, int grp, u32 target) {
    const u64* base = (const u64*)(flags + grp * 128);
    const int sl = threadIdx.x & 7;
    int guard = 0;
    for (;;) {
        const u64 v = aload(base + sl);
        const bool ok = ((u32)v >= target) && ((u32)(v >> 32) >= target);
        if (__all(ok) || ++guard > (1 << 20)) break;
        __builtin_amdgcn_s_sleep(1);
    }
    asm volatile("" ::: "memory");
}

// One-shot probe: true iff ALL 128 group flags >= target (steady-state fast path;
// latency overlaps the chunk-0 stage load). Per-wave result may differ -> only
// gates spin-waits, never barriers.
__device__ __forceinline__ bool probe128(const u32* flags, int grp, u32 target) {
    const u64 v = aload((const u64*)(flags + grp * 128) + (threadIdx.x & 63));
    return __all(((u32)v >= target) && ((u32)(v >> 32) >= target));
}

// Laggard path: spin until chunk c's 4 producer flags >= target.
__device__ __forceinline__ void wait_chunk(const u32* flags, int grp, int c, u32 target) {
    const u64* p = (const u64*)(flags + grp * 128) + 2 * c;
    int guard = 0;
    for (;;) {
        const u64 a = aload(p);
        const u64 b = aload(p + 1);
        const bool ok = ((u32)a >= target) && ((u32)(a >> 32) >= target) &&
                        ((u32)b >= target) && ((u32)(b >> 32) >= target);
        if (ok || ++guard > (1 << 20)) break;
        __builtin_amdgcn_s_sleep(1);
    }
    asm volatile("" ::: "memory");
}

// Final: spin until all 128 group flags >= target (projection gate, once).
__device__ __forceinline__ void wait_all(const u32* flags, int grp, u32 target) {
    const u64* base = (const u64*)(flags + grp * 128) + (threadIdx.x & 63);
    int guard = 0;
    for (;;) {
        const u64 v = aload(base);
        const bool ok = ((u32)v >= target) && ((u32)(v >> 32) >= target);
        if (__all(ok) || ++guard > (1 << 20)) break;
        __builtin_amdgcn_s_sleep(1);
    }
    asm volatile("" ::: "memory");
}

#define FMA4(d, s, v) do { (d).x = fmaf((s), (v).x, (d).x); (d).y = fmaf((s), (v).y, (d).y); \
                           (d).z = fmaf((s), (v).z, (d).z); (d).w = fmaf((s), (v).w, (d).w); } while (0)
#define ADD4(d, s)     do { (d).x += (s).x; (d).y += (s).y; (d).z += (s).z; (d).w += (s).w; } while (0)

// Block: 8 j x 64 b. 16 waves: wave = jq*4 + kh (jq: j-pair, kh: k-quarter).
// Per chunk each lane handles exactly one k (kc = kh*8 + ks) -> no kk loop.
// Reduction: recursive-halving shfl butterfly + 2-stage cross-kh exchange
// through LDS aliased onto the dead sH buffers; epilogue split kh0/kh2.
__global__ void __launch_bounds__(NT, 1)
lstm_fused(const float* __restrict__ x,
           const float* __restrict__ Wgx, const float* __restrict__ Wgh, const float* __restrict__ bg,
           const float* __restrict__ Wix, const float* __restrict__ Wih, const float* __restrict__ bi,
           const float* __restrict__ Wfx, const float* __restrict__ Wfh, const float* __restrict__ bf,
           const float* __restrict__ Wox, const float* __restrict__ Woh, const float* __restrict__ bo,
           const float* __restrict__ Wph, const float* __restrict__ bp,
           u32* __restrict__ flags, float* __restrict__ out)
{
    __shared__ float sW[8][HDIM][4];            // [j_local][k][gate], 128 KB
    __shared__ __align__(16) float sHraw[2 * 32 * 68];   // h dbuf, 17 KB; aliased by sS after last chunk
#define SH(B, K) (&sHraw[(B) * 2176 + (K) * 68])

    const int tid  = threadIdx.x;
    const int wave = tid >> 6;          // 0..15
    const int jq   = wave >> 2;         // j-pair index (0..3)
    const int kh   = wave & 3;          // k-quarter within chunk
    const int lane = tid & 63;
    const int ks   = lane & 7;
    const int bo8  = lane >> 3;
    const int rgB  = blockIdx.x >> 1;   // j in [8*rgB, 8*rgB+8)  == index in group
    const int bgB  = blockIdx.x & 1;    // b in [64*bgB, 64*bgB+64) == group id

    // ---- stage W once, gate-interleaved (1024 threads: 4 rows per pass) ----
    {
        auto stageW = [&](const float* Wsrc, int g) {
            #pragma unroll
            for (int it = 0; it < 2; ++it) {
                const int row = it * 4 + (tid >> 8);     // 0..7
                const int c4  = tid & 255;               // float4 column
                const float4 v = ld4(Wsrc + (size_t)(rgB * 8 + row) * HDIM + c4 * 4);
                sW[row][c4 * 4 + 0][g] = v.x;
                sW[row][c4 * 4 + 1][g] = v.y;
                sW[row][c4 * 4 + 2][g] = v.z;
                sW[row][c4 * 4 + 3][g] = v.w;
            }
        };
        stageW(Wgh, 0); stageW(Wih, 1); stageW(Wfh, 2); stageW(Woh, 3);
    }

    // epilogue cells: j = rgB*8 + jq*2 + (ks>>2); b = bgB*64 + bo8*8 + (ks&3)*2 + cell.
    const int jc = rgB * 8 + jq * 2 + (ks >> 2);
    const float4 wx4 = make_float4(Wgx[jc], Wix[jc], Wfx[jc], Wox[jc]);
    const float4 b4  = make_float4(bg[jc], bi[jc], bf[jc], bo[jc]);
    const int bloc = bgB * 64 + bo8 * 8 + (ks & 3) * 2;   // cell-0 batch index
    float cst = 0.f;                                       // my cell's c-state

    // zero h0 (production 0, buf 0) -- OWN b-half only: 8 j-rows x 32 u64
    if (tid < 256)
        astore(&g_hx[0][rgB * 8 + (tid >> 5)][bgB * 32 + (tid & 31)], 0ull);

    // publish production 0: per-wave drain, block sync (also orders sW), flag=1
    asm volatile("s_waitcnt vmcnt(0)" ::: "memory");
    __syncthreads();
    if (tid == 0)
        astore32(flags + bgB * 128 + rgB, 1u);

    const int skc = tid >> 5;                   // staging: k within chunk (0..31)
    const int sbu = tid & 31;                   // staging: u64 col within 32
    const int hb0 = bgB * 32 + sbu;             // staging: u64 offset in g_hx row
    const int swA = (0 * 2176 + 0) / 2;         // buf0 base (u64 units)
    const int swB = (1 * 2176 + 0) / 2;         // buf1 base
    const int swoff = (skc * 68) / 2 + sbu;

#define COMP(C, BUF)                                                            \
    {                                                                           \
        const int kc_ = kh * 8 + ks;                                            \
        const float4 w0 = ld4(&sW[jq * 2 + 0][(C) * 32 + kc_][0]);              \
        const float4 w1 = ld4(&sW[jq * 2 + 1][(C) * 32 + kc_][0]);              \
        const float* hr = SH(BUF, kc_);                                         \
        const float4 hA = ld4(hr + bo8 * 8);                                    \
        const float4 hB = ld4(hr + bo8 * 8 + 4);                                \
        FMA4(acc[0][0], hA.x, w0); FMA4(acc[0][1], hA.y, w0);                   \
        FMA4(acc[0][2], hA.z, w0); FMA4(acc[0][3], hA.w, w0);                   \
        FMA4(acc[0][4], hB.x, w0); FMA4(acc[0][5], hB.y, w0);                   \
        FMA4(acc[0][6], hB.z, w0); FMA4(acc[0][7], hB.w, w0);                   \
        FMA4(acc[1][0], hA.x, w1); FMA4(acc[1][1], hA.y, w1);                   \
        FMA4(acc[1][2], hA.z, w1); FMA4(acc[1][3], hA.w, w1);                   \
        FMA4(acc[1][4], hB.x, w1); FMA4(acc[1][5], hB.y, w1);                   \
        FMA4(acc[1][6], hB.z, w1); FMA4(acc[1][7], hB.w, w1);                   \
    }

    int cb_ = 0;                                // t % 3 (consume buffer)
    for (int t = 0; t < TLEN; ++t) {
        const int nb_ = (cb_ == 2) ? 0 : cb_ + 1;
        const u32 tgt = (u32)(t + 1);           // need producers done with iter t-1
        const u64* hc = &g_hx[cb_][0][0];
        u32*       hn32 = (u32*)&g_hx[nb_][0][0];

        // x for my epilogue cell (kh0 -> b, kh2 -> b+1), L1-warm
        float xv = 0.f;
        if ((kh & 1) == 0)
            xv = x[(size_t)(bloc + (kh >> 1)) * TLEN + t];

        gate16(flags, bgB, tgt);                // chunks 0..3 producers ready

        const u64* hrow = hc + (size_t)skc * 64 + hb0;
        ((u64*)sHraw)[swA + swoff] = aload(hrow);   // stage chunk 0
        u64 A = aload(hrow + 2048);     // chunk 1
        u64 B = aload(hrow + 4096);     // chunk 2
        const bool fast = probe128(flags, bgB, tgt);  // overlaps chunk-0 latency
        barrier_lds();                  // chunk-0 ds_write done; A/B in flight

        float4 acc[2][8];   // [j_local][b]; components = 4 gates. STATIC indices only.
        #pragma unroll
        for (int jl = 0; jl < 2; ++jl)
            #pragma unroll
            for (int cb = 0; cb < 8; ++cb)
                acc[jl][cb] = make_float4(0.f, 0.f, 0.f, 0.f);

        #pragma unroll 1
        for (int cc = 0; cc < 16; ++cc) {
            const int e0 = cc * 2;
            COMP(e0, 0);
            ((u64*)sHraw)[swB + swoff] = A;                  // chunk e0+1
            if (e0 + 3 < 32) {
                if (!fast) wait_chunk(flags, bgB, e0 + 3, tgt);
                A = aload(hrow + (size_t)(e0 + 3) * 2048);
            }
            barrier_lds();
            COMP(e0 + 1, 1);
            if (e0 + 2 < 32) ((u64*)sHraw)[swA + swoff] = B; // chunk e0+2
            if (e0 + 4 < 32) {
                if (!fast) wait_chunk(flags, bgB, e0 + 4, tgt);
                B = aload(hrow + (size_t)(e0 + 4) * 2048);
            }
            barrier_lds();
        }
        // loop-final barrier: all sH reads done -> sS alias safe

        // ---- intra-wave recursive-halving reduction over ks (56 shfl) ----
        float4 r1[8];
        #pragma unroll
        for (int i = 0; i < 8; ++i) {
            const float4 fs = (ks & 4) ? acc[0][i] : acc[1][i];
            float4 fr;
            fr.x = __shfl_xor(fs.x, 4); fr.y = __shfl_xor(fs.y, 4);
            fr.z = __shfl_xor(fs.z, 4); fr.w = __shfl_xor(fs.w, 4);
            const float4 fk = (ks & 4) ? acc[1][i] : acc[0][i];
            r1[i] = make_float4(fk.x + fr.x, fk.y + fr.y, fk.z + fr.z, fk.w + fr.w);
        }
        float4 r2[4];
        #pragma unroll
        for (int i = 0; i < 4; ++i) {
            const float4 fs = (ks & 2) ? r1[i] : r1[i + 4];
            float4 fr;
            fr.x = __shfl_xor(fs.x, 2); fr.y = __shfl_xor(fs.y, 2);
            fr.z = __shfl_xor(fs.z, 2); fr.w = __shfl_xor(fs.w, 2);
            const float4 fk = (ks & 2) ? r1[i + 4] : r1[i];
            r2[i] = make_float4(fk.x + fr.x, fk.y + fr.y, fk.z + fr.z, fk.w + fr.w);
        }
        float4 q0, q1;
        {
            const float4 fs0 = (ks & 1) ? r2[0] : r2[2];
            const float4 fs1 = (ks & 1) ? r2[1] : r2[3];
            float4 fr0, fr1;
            fr0.x = __shfl_xor(fs0.x, 1); fr0.y = __shfl_xor(fs0.y, 1);
            fr0.z = __shfl_xor(fs0.z, 1); fr0.w = __shfl_xor(fs0.w, 1);
            fr1.x = __shfl_xor(fs1.x, 1); fr1.y = __shfl_xor(fs1.y, 1);
            fr1.z = __shfl_xor(fs1.z, 1); fr1.w = __shfl_xor(fs1.w, 1);
            const float4 fk0 = (ks & 1) ? r2[2] : r2[0];
            const float4 fk1 = (ks & 1) ? r2[3] : r2[1];
            q0 = make_float4(fk0.x + fr0.x, fk0.y + fr0.y, fk0.z + fr0.z, fk0.w + fr0.w);
            q1 = make_float4(fk1.x + fr1.x, fk1.y + fr1.y, fk1.z + fr1.z, fk1.w + fr1.w);
        }
        // q0,q1 = partial (this kh) preacts for cells (jc, bloc) and (jc, bloc+1)

        // ---- cross-kh reduction via LDS aliased onto dead sH ----
        float4* sS = (float4*)sHraw;    // 1024 f4 = 16 KB <= 17.4 KB
        if (kh & 1) {                   // kh1 -> slot(jq,0), kh3 -> slot(jq,1)
            const int sl = ((jq * 2 + (kh >> 1)) * 64 + lane) * 2;
            sS[sl]     = q0;
            sS[sl + 1] = q1;
        }
        barrier_lds();
        if ((kh & 1) == 0) {            // kh0 adds kh1; kh2 adds kh3
            const int sl = ((jq * 2 + (kh >> 1)) * 64 + lane) * 2;
            ADD4(q0, sS[sl]);
            ADD4(q1, sS[sl + 1]);
        }
        // stage 2: kh0 surrenders q1, kh2 surrenders q0 (each keeps its cell)
        if (kh == 0) sS[((jq * 2 + 0) * 64 + lane) * 2 + 1] = q1;
        if (kh == 2) sS[((jq * 2 + 1) * 64 + lane) * 2 + 0] = q0;
        barrier_lds();

        if ((kh & 1) == 0) {
            float4 qq;
            if (kh == 0) {
                ADD4(q0, sS[((jq * 2 + 1) * 64 + lane) * 2 + 0]);
                qq = q0;
            } else {
                ADD4(q1, sS[((jq * 2 + 0) * 64 + lane) * 2 + 1]);
                qq = q1;
            }
            FMA4(qq, xv, wx4);
            qq.x += b4.x; qq.y += b4.y; qq.z += b4.z; qq.w += b4.w;
            const float g_ = tanhf(qq.x);
            const float i_ = 1.f / (1.f + expf(-qq.y));
            const float f_ = 1.f / (1.f + expf(-qq.z));
            const float o_ = 1.f / (1.f + expf(-qq.w));
            cst = g_ * i_ + cst * f_;
            const float hv = tanhf(cst) * o_;
            u32 bits; __builtin_memcpy(&bits, &hv, 4);
            astore32(hn32 + (size_t)jc * 128 + bloc + (kh >> 1), bits);
        }

        // ---- publish production t+1: drain h writes, block sync, bump flag ----
        asm volatile("s_waitcnt vmcnt(0)" ::: "memory");
        __syncthreads();                // also protects sS -> next-step sH reuse
        if (tid == 0)
            astore32(flags + bgB * 128 + rgB, (u32)(t + 2));

        cb_ = nb_;
    } // t
#undef COMP

    // ---- final projection: out = h_final @ W_ph + bias_p.
    // Final h = production TLEN, in buf TLEN % 3 == 1. Gate on all flags.
    wait_all(flags, bgB, (u32)(TLEN + 1));
    if (rgB < 64) {
        const int b = bgB * 64 + rgB;
        float part[CDIM];
        #pragma unroll
        for (int c2 = 0; c2 < CDIM; ++c2) part[c2] = 0.f;
        for (int k = tid; k < HDIM; k += NT) {
            const u64 hvu = aload(&g_hx[TLEN % 3][k][b >> 1]);
            float2 hv2; __builtin_memcpy(&hv2, &hvu, 8);
            const float hvv = (b & 1) ? hv2.y : hv2.x;
            #pragma unroll
            for (int c2 = 0; c2 < CDIM; ++c2)
                part[c2] = fmaf(hvv, Wph[(size_t)k * CDIM + c2], part[c2]);
        }
        float* red = (float*)&sW[0][0][0];   // reuse dead W LDS (48 KB needed)
        #pragma unroll
        for (int c2 = 0; c2 < CDIM; ++c2) red[tid * 12 + c2] = part[c2];
        __syncthreads();
        for (int s = NT / 2; s > 0; s >>= 1) {
            if (tid < s) {
                #pragma unroll
                for (int c2 = 0; c2 < CDIM; ++c2)
                    red[tid * 12 + c2] += red[(tid + s) * 12 + c2];
            }
            __syncthreads();
        }
        if (tid < CDIM) out[(size_t)b * CDIM + tid] = red[tid] + bp[tid];
    }
}

extern "C" void kernel_launch(void* const* d_in, const int* in_sizes, int n_in,
                              void* d_out, int out_size, void* d_ws, size_t ws_size,
                              hipStream_t stream) {
    const float* x   = (const float*)d_in[0];
    const float* Wgx = (const float*)d_in[1];
    const float* Wgh = (const float*)d_in[2];
    const float* bg  = (const float*)d_in[3];
    const float* Wix = (const float*)d_in[4];
    const float* Wih = (const float*)d_in[5];
    const float* bi  = (const float*)d_in[6];
    const float* Wfx = (const float*)d_in[7];
    const float* Wfh = (const float*)d_in[8];
    const float* bf  = (const float*)d_in[9];
    const float* Wox = (const float*)d_in[10];
    const float* Woh = (const float*)d_in[11];
    const float* bo  = (const float*)d_in[12];
    const float* Wph = (const float*)d_in[13];
    const float* bp  = (const float*)d_in[14];
    u32* flags = (u32*)d_ws;               // u32[2][128] monotonic production counters
    float* out = (float*)d_out;

    hipMemsetAsync(d_ws, 0, 2 * 128 * sizeof(u32), stream);   // capturable node

    void* args[] = {&x, &Wgx, &Wgh, &bg, &Wix, &Wih, &bi, &Wfx, &Wfh, &bf,
                    &Wox, &Woh, &bo, &Wph, &bp, &flags, &out};
    hipError_t rc = hipLaunchCooperativeKernel((void*)lstm_fused, dim3(NWG), dim3(NT),
                                               args, 0, stream);
    if (rc != hipSuccess) {
        // Dataflow sync needs no cooperative-runtime support; 256 blocks at
        // 1 block/CU are fully co-resident under a regular launch too.
        lstm_fused<<<dim3(NWG), dim3(NT), 0, stream>>>(
            x, Wgx, Wgh, bg, Wix, Wih, bi, Wfx, Wfh, bf,
            Wox, Woh, bo, Wph, bp, flags, out);
    }
}